// Round 14
// baseline (381.043 us; speedup 1.0000x reference)
//
#include <hip/hip_runtime.h>
#include <hip/hip_bf16.h>
#include <math.h>

typedef short short8_t __attribute__((ext_vector_type(8)));
typedef float floatx4  __attribute__((ext_vector_type(4)));
typedef float floatx2  __attribute__((ext_vector_type(2)));
typedef unsigned int uint;

// ---------------- bf16 helpers (RNE) ----------------------------------------

__device__ inline unsigned short f2b(float f) {
    uint u = __float_as_uint(f);
    u += 0x7fff + ((u >> 16) & 1);
    return (unsigned short)(u >> 16);
}
__device__ inline uint pack2(float a, float b) {
    return (uint)f2b(a) | ((uint)f2b(b) << 16);
}
__device__ inline float b2f(unsigned short h) { return __uint_as_float((uint)h << 16); }
__device__ inline float blo(uint v) { return __uint_as_float(v << 16); }
__device__ inline float bhi(uint v) { return __uint_as_float(v & 0xffff0000u); }

// ---------------- fp8 (e4m3) helpers ------------------------------------------

__device__ inline uint enc4_fp8(float f0, float f1, float f2, float f3) {
    uint v = __builtin_amdgcn_cvt_pk_fp8_f32(f0, f1, 0, false);
    v = __builtin_amdgcn_cvt_pk_fp8_f32(f2, f3, v, true);
    return v;
}
__device__ inline unsigned char enc1_fp8(float f) {
    return (unsigned char)(__builtin_amdgcn_cvt_pk_fp8_f32(f, f, 0, false) & 0xff);
}

// ---------------- phase A mega-kernel -----------------------------------------
// Lessons: R10 — atomic count is pinned ~45-50us regardless of ILP depth;
// R13 — 8-replica XCD-local histograms DON'T help (atomics execute at a
// fixed home point, not the issuing XCD's L2). So treat the histogram as a
// fixed-cost phase and hide independent work inside it:
//   grid = [count | cvt_x(fp8 only) | cvt_w | graph_bounds | GEMM x@Wr1^T].
// The GEMM (layer-1 direct half, graph-independent by linearity) rides the
// ~98%-idle MFMA/VALU pipes during the atomic phase.
// R11 lesson: never fuse the latency-bound gather into an MFMA kernel.

__global__ __launch_bounds__(256) void k_phase_a(
    const int* __restrict__ dst, int* __restrict__ deg, int* __restrict__ epos, int E,
    const float* __restrict__ x, unsigned char* __restrict__ xf8, int nX,
    const float* __restrict__ Wl1, const float* __restrict__ Wr1,
    const float* __restrict__ Wl2, const float* __restrict__ Wr2,
    unsigned short* __restrict__ wbuf,
    const int* __restrict__ batch, int* __restrict__ gstart, int N, int G,
    unsigned short* __restrict__ hr1, int n_nodes,
    int bCount, int bCvtX, int bCvtW) {
    __shared__ __align__(16) short As[128 * 32];
    int b = blockIdx.x;
    if (b < bCount) {
        int e = (b * 256 + threadIdx.x) * 4;
        if (e + 3 < E) {
            int4 d4 = *(const int4*)(dst + e);
            int4 p;
            p.x = atomicAdd(&deg[d4.x], 1);
            p.y = atomicAdd(&deg[d4.y], 1);
            p.z = atomicAdd(&deg[d4.z], 1);
            p.w = atomicAdd(&deg[d4.w], 1);
            *(int4*)(epos + e) = p;
        } else {
            for (int k = e; k < E; ++k) epos[k] = atomicAdd(&deg[dst[k]], 1);
        }
    } else if (b < bCount + bCvtX) {
        int i = ((b - bCount) * 256 + threadIdx.x) * 8;
        if (i < nX) {
            float4 v0 = *(const float4*)(x + i);
            float4 v1 = *(const float4*)(x + i + 4);
            uint2 of;
            of.x = enc4_fp8(v0.x, v0.y, v0.z, v0.w);
            of.y = enc4_fp8(v1.x, v1.y, v1.z, v1.w);
            *(uint2*)(xf8 + i) = of;
        }
    } else if (b < bCount + bCvtX + bCvtW) {
        int i = (b - bCount - bCvtX) * 256 + threadIdx.x;
        if (i < 49152) {
            float v;
            if (i < 8192)       v = Wl1[i];
            else if (i < 16384) v = Wr1[i - 8192];
            else if (i < 32768) v = Wl2[i - 16384];
            else                v = Wr2[i - 32768];
            wbuf[i] = f2b(v);
        }
    } else if (b == bCount + bCvtX + bCvtW) {
        for (int g = threadIdx.x; g <= G; g += 256) {
            if (g == G) { gstart[G] = N; continue; }
            int lo = 0, hi = N;
            while (lo < hi) {
                int mid = (lo + hi) >> 1;
                if (batch[mid] < g) lo = mid + 1; else hi = mid;
            }
            gstart[g] = lo;
        }
    } else {
        // GEMM: hr1 = x @ Wr1^T (fp32 in, bf16 MFMA, bf16 out). 128x128 tile.
        int bg = b - (bCount + bCvtX + bCvtW + 1);
        int node0 = bg * 128;
        int tid  = threadIdx.x;
        int lane = tid & 63;
        int wave = tid >> 6;
        int quad = lane >> 4;
        int lr   = lane & 15;
        floatx4 acc[8][2];
#pragma unroll
        for (int mi = 0; mi < 8; ++mi)
#pragma unroll
            for (int ni = 0; ni < 2; ++ni)
                acc[mi][ni] = (floatx4){0.f, 0.f, 0.f, 0.f};
        int srow = tid >> 2;
        int sslot = tid & 3;
#pragma unroll
        for (int c = 0; c < 2; ++c) {
            int kb = c * 32;
            __syncthreads();
            {
                int n1 = node0 + srow;       if (n1 >= n_nodes) n1 = n_nodes - 1;
                int n2 = node0 + srow + 64;  if (n2 >= n_nodes) n2 = n_nodes - 1;
                float4 a0 = *(const float4*)(x + (size_t)n1 * 64 + kb + sslot * 8);
                float4 a1 = *(const float4*)(x + (size_t)n1 * 64 + kb + sslot * 8 + 4);
                float4 c0 = *(const float4*)(x + (size_t)n2 * 64 + kb + sslot * 8);
                float4 c1 = *(const float4*)(x + (size_t)n2 * 64 + kb + sslot * 8 + 4);
                uint4 u1, u2;
                u1.x = pack2(a0.x, a0.y); u1.y = pack2(a0.z, a0.w);
                u1.z = pack2(a1.x, a1.y); u1.w = pack2(a1.z, a1.w);
                u2.x = pack2(c0.x, c0.y); u2.y = pack2(c0.z, c0.w);
                u2.z = pack2(c1.x, c1.y); u2.w = pack2(c1.z, c1.w);
                *(uint4*)(&As[srow * 32 + sslot * 8]) = u1;
                *(uint4*)(&As[(srow + 64) * 32 + sslot * 8]) = u2;
            }
            __syncthreads();
            short8_t bfrag[2];
#pragma unroll
            for (int ni = 0; ni < 2; ++ni) {
                int j = wave * 32 + ni * 16 + lr;
                float4 wa = *(const float4*)(Wr1 + (size_t)j * 64 + kb + quad * 8);
                float4 wb = *(const float4*)(Wr1 + (size_t)j * 64 + kb + quad * 8 + 4);
                short8_t f;
                f[0] = (short)f2b(wa.x); f[1] = (short)f2b(wa.y);
                f[2] = (short)f2b(wa.z); f[3] = (short)f2b(wa.w);
                f[4] = (short)f2b(wb.x); f[5] = (short)f2b(wb.y);
                f[6] = (short)f2b(wb.z); f[7] = (short)f2b(wb.w);
                bfrag[ni] = f;
            }
#pragma unroll
            for (int mi = 0; mi < 8; ++mi) {
                short8_t af = *(const short8_t*)(&As[(mi * 16 + lr) * 32 + quad * 8]);
                acc[mi][0] = __builtin_amdgcn_mfma_f32_16x16x32_bf16(af, bfrag[0], acc[mi][0], 0, 0, 0);
                acc[mi][1] = __builtin_amdgcn_mfma_f32_16x16x32_bf16(af, bfrag[1], acc[mi][1], 0, 0, 0);
            }
        }
        int j0 = wave * 32 + lr;
#pragma unroll
        for (int mi = 0; mi < 8; ++mi) {
#pragma unroll
            for (int r = 0; r < 4; ++r) {
                int node = node0 + mi * 16 + quad * 4 + r;
                if (node < n_nodes) {
                    hr1[(size_t)node * 128 + j0]      = f2b(acc[mi][0][r]);
                    hr1[(size_t)node * 128 + j0 + 16] = f2b(acc[mi][1][r]);
                }
            }
        }
    }
}

// ---------------- scan (3-phase, single histogram) ----------------------------

__global__ void k_block_sum(const int* __restrict__ deg, int* __restrict__ bsum, int n) {
    __shared__ int red[256];
    int i = blockIdx.x * 256 + threadIdx.x;
    red[threadIdx.x] = (i < n) ? deg[i] : 0;
    __syncthreads();
#pragma unroll
    for (int off = 128; off > 0; off >>= 1) {
        if (threadIdx.x < off) red[threadIdx.x] += red[threadIdx.x + off];
        __syncthreads();
    }
    if (threadIdx.x == 0) bsum[blockIdx.x] = red[0];
}

__global__ void k_scan_bsum(int* __restrict__ bsum, int nb) {
    __shared__ int s[512];
    int t = threadIdx.x;
    int v = (t < nb) ? bsum[t] : 0;
    s[t] = v;
    __syncthreads();
#pragma unroll
    for (int off = 1; off < 512; off <<= 1) {
        int u = (t >= off) ? s[t - off] : 0;
        __syncthreads();
        s[t] += u;
        __syncthreads();
    }
    if (t < nb) bsum[t] = s[t] - v;
}

__global__ void k_scan_final(const int* __restrict__ deg, const int* __restrict__ bsum,
                             int* __restrict__ row_start, int n) {
    __shared__ int s[256];
    int i = blockIdx.x * 256 + threadIdx.x;
    int v = (i < n) ? deg[i] : 0;
    s[threadIdx.x] = v;
    __syncthreads();
#pragma unroll
    for (int off = 1; off < 256; off <<= 1) {
        int u = (threadIdx.x >= off) ? s[threadIdx.x - off] : 0;
        __syncthreads();
        s[threadIdx.x] += u;
        __syncthreads();
    }
    int excl = s[threadIdx.x] - v + bsum[blockIdx.x];
    if (i < n) row_start[i] = excl;
    if (i == n - 1) row_start[n] = excl + v;
}

// atomic-free placement, 8 edges/thread. Packed CSR (4MB, L2-resident;
// R9 lesson: strided buckets caused 16x write amplification).
__global__ void k_place(const int* __restrict__ src, const int* __restrict__ dst,
                        const int* __restrict__ row_start, const int* __restrict__ epos,
                        int* __restrict__ csr_src, int E) {
    int e = (blockIdx.x * blockDim.x + threadIdx.x) * 8;
    if (e + 7 < E) {
        int4 d0 = *(const int4*)(dst + e);
        int4 d1 = *(const int4*)(dst + e + 4);
        int4 p0 = *(const int4*)(epos + e);
        int4 p1 = *(const int4*)(epos + e + 4);
        int4 s0 = *(const int4*)(src + e);
        int4 s1 = *(const int4*)(src + e + 4);
        int r0 = row_start[d0.x];
        int r1 = row_start[d0.y];
        int r2 = row_start[d0.z];
        int r3 = row_start[d0.w];
        int r4 = row_start[d1.x];
        int r5 = row_start[d1.y];
        int r6 = row_start[d1.z];
        int r7 = row_start[d1.w];
        csr_src[r0 + p0.x] = s0.x;
        csr_src[r1 + p0.y] = s0.y;
        csr_src[r2 + p0.z] = s0.z;
        csr_src[r3 + p0.w] = s0.w;
        csr_src[r4 + p1.x] = s1.x;
        csr_src[r5 + p1.y] = s1.y;
        csr_src[r6 + p1.z] = s1.z;
        csr_src[r7 + p1.w] = s1.w;
    } else {
        for (int k = e; k < E; ++k) csr_src[row_start[dst[k]] + epos[k]] = src[k];
    }
}

// ---------------- mean aggregation (fp8 in, bf16 out, fp32 accumulate) -------

#define ACCF8(v)                                                        \
    { floatx2 f = __builtin_amdgcn_cvt_pk_f32_fp8((v).x, false);        \
      a[0] += f[0]; a[1] += f[1];                                       \
      f = __builtin_amdgcn_cvt_pk_f32_fp8((v).x, true);                 \
      a[2] += f[0]; a[3] += f[1];                                       \
      f = __builtin_amdgcn_cvt_pk_f32_fp8((v).y, false);                \
      a[4] += f[0]; a[5] += f[1];                                       \
      f = __builtin_amdgcn_cvt_pk_f32_fp8((v).y, true);                 \
      a[6] += f[0]; a[7] += f[1]; }

// K=64: row = 64 B fp8. 8 edge-slots x 8 lanes x uint2; 2-deep unroll.
__global__ void k_gather1(const unsigned char* __restrict__ xf8,
                          const int* __restrict__ row_start,
                          const int* __restrict__ csr_src,
                          unsigned short* __restrict__ agg, int n_nodes) {
    int tid = threadIdx.x;
    int node = blockIdx.x * 4 + (tid >> 6);
    if (node >= n_nodes) return;
    int lane = tid & 63;
    int grp = lane >> 3;
    int lp  = lane & 7;
    int s = row_start[node];
    int e = row_start[node + 1];
    float a[8];
#pragma unroll
    for (int q = 0; q < 8; ++q) a[q] = 0.f;
    int i = s + grp;
    for (; i + 8 < e; i += 16) {
        int u0 = csr_src[i];
        int u1 = csr_src[i + 8];
        uint2 v0 = *(const uint2*)(xf8 + (size_t)u0 * 64 + lp * 8);
        uint2 v1 = *(const uint2*)(xf8 + (size_t)u1 * 64 + lp * 8);
        ACCF8(v0);
        ACCF8(v1);
    }
    if (i < e) {
        int u0 = csr_src[i];
        uint2 v0 = *(const uint2*)(xf8 + (size_t)u0 * 64 + lp * 8);
        ACCF8(v0);
    }
#pragma unroll
    for (int q = 0; q < 8; ++q) {
        a[q] += __shfl_xor(a[q], 8);
        a[q] += __shfl_xor(a[q], 16);
        a[q] += __shfl_xor(a[q], 32);
    }
    if (grp == 0) {
        int d = e - s;
        float scale = (d > 0) ? (1.f / (float)d) : 1.f;
        uint4 o;
        o.x = pack2(a[0] * scale, a[1] * scale);
        o.y = pack2(a[2] * scale, a[3] * scale);
        o.z = pack2(a[4] * scale, a[5] * scale);
        o.w = pack2(a[6] * scale, a[7] * scale);
        *(uint4*)(agg + (size_t)node * 64 + lp * 8) = o;
    }
}

// gather2 (K=128 fp8 rows) + fused GEMM hr2 = h1 @ Wr2^T (extra blocks).
__global__ __launch_bounds__(256) void k_gather2_mix(
    const unsigned char* __restrict__ h1f8,
    const int* __restrict__ row_start, const int* __restrict__ csr_src,
    unsigned short* __restrict__ agg,
    const unsigned short* __restrict__ h1, const unsigned short* __restrict__ Wr2b,
    unsigned short* __restrict__ hr2, int n_nodes, int bG2) {
    __shared__ __align__(16) short As[128 * 32];
    int b = blockIdx.x;
    if (b < bG2) {
        int tid = threadIdx.x;
        int node = b * 4 + (tid >> 6);
        if (node >= n_nodes) return;
        int lane = tid & 63;
        int grp = lane >> 4;
        int lp  = lane & 15;
        int s = row_start[node];
        int e = row_start[node + 1];
        float a[8];
#pragma unroll
        for (int q = 0; q < 8; ++q) a[q] = 0.f;
        int i = s + grp;
        for (; i + 4 < e; i += 8) {
            int u0 = csr_src[i];
            int u1 = csr_src[i + 4];
            uint2 v0 = *(const uint2*)(h1f8 + (size_t)u0 * 128 + lp * 8);
            uint2 v1 = *(const uint2*)(h1f8 + (size_t)u1 * 128 + lp * 8);
            ACCF8(v0);
            ACCF8(v1);
        }
        if (i < e) {
            int u0 = csr_src[i];
            uint2 v0 = *(const uint2*)(h1f8 + (size_t)u0 * 128 + lp * 8);
            ACCF8(v0);
        }
#pragma unroll
        for (int q = 0; q < 8; ++q) {
            a[q] += __shfl_xor(a[q], 16);
            a[q] += __shfl_xor(a[q], 32);
        }
        if (grp == 0) {
            int d = e - s;
            float scale = (d > 0) ? (1.f / (float)d) : 1.f;
            uint4 o;
            o.x = pack2(a[0] * scale, a[1] * scale);
            o.y = pack2(a[2] * scale, a[3] * scale);
            o.z = pack2(a[4] * scale, a[5] * scale);
            o.w = pack2(a[6] * scale, a[7] * scale);
            *(uint4*)(agg + (size_t)node * 128 + lp * 8) = o;
        }
    } else {
        // GEMM: hr2 = h1 @ Wr2^T (bf16 in/out), 128x128 tile, K=128.
        int bg = b - bG2;
        int node0 = bg * 128;
        int tid  = threadIdx.x;
        int lane = tid & 63;
        int wave = tid >> 6;
        int quad = lane >> 4;
        int lr   = lane & 15;
        floatx4 acc[8][2];
#pragma unroll
        for (int mi = 0; mi < 8; ++mi)
#pragma unroll
            for (int ni = 0; ni < 2; ++ni)
                acc[mi][ni] = (floatx4){0.f, 0.f, 0.f, 0.f};
        int srow = tid >> 2;
        int sslot = tid & 3;
#pragma unroll
        for (int c = 0; c < 4; ++c) {
            int kb = c * 32;
            __syncthreads();
            {
                int n1 = node0 + srow;       if (n1 >= n_nodes) n1 = n_nodes - 1;
                int n2 = node0 + srow + 64;  if (n2 >= n_nodes) n2 = n_nodes - 1;
                uint4 v1 = *(const uint4*)(h1 + (size_t)n1 * 128 + kb + sslot * 8);
                uint4 v2 = *(const uint4*)(h1 + (size_t)n2 * 128 + kb + sslot * 8);
                *(uint4*)(&As[srow * 32 + sslot * 8]) = v1;
                *(uint4*)(&As[(srow + 64) * 32 + sslot * 8]) = v2;
            }
            __syncthreads();
            short8_t bfrag[2];
#pragma unroll
            for (int ni = 0; ni < 2; ++ni) {
                int j = wave * 32 + ni * 16 + lr;
                bfrag[ni] = *(const short8_t*)(Wr2b + (size_t)j * 128 + kb + quad * 8);
            }
#pragma unroll
            for (int mi = 0; mi < 8; ++mi) {
                short8_t af = *(const short8_t*)(&As[(mi * 16 + lr) * 32 + quad * 8]);
                acc[mi][0] = __builtin_amdgcn_mfma_f32_16x16x32_bf16(af, bfrag[0], acc[mi][0], 0, 0, 0);
                acc[mi][1] = __builtin_amdgcn_mfma_f32_16x16x32_bf16(af, bfrag[1], acc[mi][1], 0, 0, 0);
            }
        }
        int j0 = wave * 32 + lr;
#pragma unroll
        for (int mi = 0; mi < 8; ++mi) {
#pragma unroll
            for (int r = 0; r < 4; ++r) {
                int node = node0 + mi * 16 + quad * 4 + r;
                if (node < n_nodes) {
                    hr2[(size_t)node * 128 + j0]      = f2b(acc[mi][0][r]);
                    hr2[(size_t)node * 128 + j0 + 16] = f2b(acc[mi][1][r]);
                }
            }
        }
    }
}

// ---------------- MFMA linear (Wl-half only): out = relu(agg@Wl.T + bl + hr) -
// hr is the precomputed direct half (bf16). In-place safe: hr may alias out
// (same thread reads hr[node,j] then writes out[node,j]).

template <int K, bool F8OUT>
__global__ __launch_bounds__(256) void k_linear_l(
    const unsigned short* __restrict__ agg,
    const unsigned short* __restrict__ Wlb,  const float* __restrict__ bl,
    const unsigned short* __restrict__ hr, unsigned short* __restrict__ out,
    unsigned char* __restrict__ outf8, int n_nodes) {
    constexpr int NCH = K / 32;
    __shared__ __align__(16) short As[128 * 32];

    int tid  = threadIdx.x;
    int lane = tid & 63;
    int wave = tid >> 6;
    int quad = lane >> 4;
    int lr   = lane & 15;
    int node0 = blockIdx.x * 128;

    floatx4 acc[8][2];
#pragma unroll
    for (int mi = 0; mi < 8; ++mi)
#pragma unroll
        for (int ni = 0; ni < 2; ++ni)
            acc[mi][ni] = (floatx4){0.f, 0.f, 0.f, 0.f};

    int srow = tid >> 2;
    int sslot = tid & 3;

#pragma unroll
    for (int c = 0; c < NCH; ++c) {
        int kb = c * 32;
        __syncthreads();
        {
            int n1 = node0 + srow;       if (n1 >= n_nodes) n1 = n_nodes - 1;
            int n2 = node0 + srow + 64;  if (n2 >= n_nodes) n2 = n_nodes - 1;
            uint4 v1 = *(const uint4*)(agg + (size_t)n1 * K + kb + sslot * 8);
            uint4 v2 = *(const uint4*)(agg + (size_t)n2 * K + kb + sslot * 8);
            *(uint4*)(&As[srow * 32 + sslot * 8]) = v1;
            *(uint4*)(&As[(srow + 64) * 32 + sslot * 8]) = v2;
        }
        __syncthreads();

        short8_t bfrag[2];
#pragma unroll
        for (int ni = 0; ni < 2; ++ni) {
            int j = wave * 32 + ni * 16 + lr;
            bfrag[ni] = *(const short8_t*)(Wlb + (size_t)j * K + kb + quad * 8);
        }
#pragma unroll
        for (int mi = 0; mi < 8; ++mi) {
            short8_t af = *(const short8_t*)(&As[(mi * 16 + lr) * 32 + quad * 8]);
            acc[mi][0] = __builtin_amdgcn_mfma_f32_16x16x32_bf16(af, bfrag[0], acc[mi][0], 0, 0, 0);
            acc[mi][1] = __builtin_amdgcn_mfma_f32_16x16x32_bf16(af, bfrag[1], acc[mi][1], 0, 0, 0);
        }
    }

    float b0 = bl[wave * 32 + lr];
    float b1 = bl[wave * 32 + 16 + lr];
    int j0 = wave * 32 + lr;
#pragma unroll
    for (int mi = 0; mi < 8; ++mi) {
#pragma unroll
        for (int r = 0; r < 4; ++r) {
            int node = node0 + mi * 16 + quad * 4 + r;
            if (node < n_nodes) {
                float h0 = b2f(hr[(size_t)node * 128 + j0]);
                float h1v = b2f(hr[(size_t)node * 128 + j0 + 16]);
                float v0 = fmaxf(acc[mi][0][r] + b0 + h0, 0.f);
                float v1 = fmaxf(acc[mi][1][r] + b1 + h1v, 0.f);
                out[(size_t)node * 128 + j0]      = f2b(v0);
                out[(size_t)node * 128 + j0 + 16] = f2b(v1);
                if (F8OUT) {
                    outf8[(size_t)node * 128 + j0]      = enc1_fp8(v0);
                    outf8[(size_t)node * 128 + j0 + 16] = enc1_fp8(v1);
                }
            }
        }
    }
}

// ---------------- fused pool + head -------------------------------------------

__global__ __launch_bounds__(256) void k_pool_head(const unsigned short* __restrict__ h2b,
                                                   const int* __restrict__ gstart,
                                                   const float* __restrict__ Wout,
                                                   const float* __restrict__ bout,
                                                   float* __restrict__ out) {
    int g = blockIdx.x;
    int s = gstart[g], e = gstart[g + 1];
    int lane = threadIdx.x & 63;
    int wave = threadIdx.x >> 6;
    float ax = 0.f, ay = 0.f;
    for (int n = s + wave; n < e; n += 4) {
        uint v = ((const uint*)(h2b + (size_t)n * 128))[lane];
        ax += blo(v);
        ay += bhi(v);
    }
    __shared__ float2 red[4][64];
    red[wave][lane] = make_float2(ax, ay);
    __syncthreads();
    if (wave == 0) {
        float2 a = red[0][lane], b = red[1][lane], c = red[2][lane], d = red[3][lane];
        float cnt = (float)(e - s);
        float inv = (cnt > 0.f) ? (1.f / cnt) : 1.f;
        float px = (a.x + b.x + c.x + d.x) * inv;
        float py = (a.y + b.y + c.y + d.y) * inv;
        float2 w0 = ((const float2*)(Wout))[lane];
        float2 w1 = ((const float2*)(Wout + 128))[lane];
        float d0 = px * w0.x + py * w0.y;
        float d1 = px * w1.x + py * w1.y;
#pragma unroll
        for (int m = 32; m > 0; m >>= 1) {
            d0 += __shfl_xor(d0, m);
            d1 += __shfl_xor(d1, m);
        }
        if (lane == 0) {
            float l0 = d0 + bout[0];
            float l1 = d1 + bout[1];
            float mx = fmaxf(l0, l1);
            float lse = mx + logf(expf(l0 - mx) + expf(l1 - mx));
            out[g * 2 + 0] = l0 - lse;
            out[g * 2 + 1] = l1 - lse;
        }
    }
}

// ---------------- launch -----------------------------------------------------

static inline size_t alignUp(size_t x, size_t a) { return (x + a - 1) & ~(a - 1); }

extern "C" void kernel_launch(void* const* d_in, const int* in_sizes, int n_in,
                              void* d_out, int out_size, void* d_ws, size_t ws_size,
                              hipStream_t stream) {
    const float* x    = (const float*)d_in[0];
    const int*   ei   = (const int*)d_in[1];
    const int*   batch= (const int*)d_in[2];
    const float* Wl1  = (const float*)d_in[3];
    const float* bl1  = (const float*)d_in[4];
    const float* Wr1  = (const float*)d_in[5];
    const float* Wl2  = (const float*)d_in[6];
    const float* bl2  = (const float*)d_in[7];
    const float* Wr2  = (const float*)d_in[8];
    const float* Wout = (const float*)d_in[9];
    const float* bout = (const float*)d_in[10];
    float* out = (float*)d_out;

    const int N = in_sizes[0] / 64;   // 100000
    const int E = in_sizes[1] / 2;    // 1000000
    const int G = out_size / 2;       // 256

    const int* src = ei;
    const int* dst = ei + E;

    const int nScanBlocks = (N + 255) / 256;

    // workspace layout (~92 MB; hr1 aliases h1, hr2 aliases h2b — in-place
    // read-then-write by the same thread in the linear epilogues)
    char* ws = (char*)d_ws;
    size_t off = 0;
    int*   deg       = (int*)(ws + off); off = alignUp(off + (size_t)N * 4, 256);
    int*   row_start = (int*)(ws + off); off = alignUp(off + (size_t)(N + 1) * 4, 256);
    int*   epos      = (int*)(ws + off); off = alignUp(off + (size_t)E * 4, 256);
    int*   csr_src   = (int*)(ws + off); off = alignUp(off + (size_t)E * 4, 256);
    int*   bsum      = (int*)(ws + off); off = alignUp(off + (size_t)512 * 4, 256);
    int*   gstart    = (int*)(ws + off); off = alignUp(off + (size_t)(G + 1) * 4, 256);
    unsigned char*  xf8  = (unsigned char*)(ws + off);  off = alignUp(off + (size_t)N * 64, 256);
    unsigned short* wbuf = (unsigned short*)(ws + off); off = alignUp(off + (size_t)49152 * 2, 256);
    unsigned short* agg1 = (unsigned short*)(ws + off); off = alignUp(off + (size_t)N * 64 * 2, 256);
    unsigned short* h1   = (unsigned short*)(ws + off); off = alignUp(off + (size_t)N * 128 * 2, 256);
    unsigned char*  h1f8 = (unsigned char*)(ws + off);  off = alignUp(off + (size_t)N * 128, 256);
    unsigned short* agg2 = (unsigned short*)(ws + off); off = alignUp(off + (size_t)N * 128 * 2, 256);
    unsigned short* h2b  = (unsigned short*)(ws + off); off = alignUp(off + (size_t)N * 128 * 2, 256);
    (void)ws_size;

    unsigned short* hr1 = h1;    // alias: phase_a writes hr1, linear1 rewrites as h1
    unsigned short* hr2 = h2b;   // alias: gather2_mix writes hr2, linear2 rewrites as h2b

    unsigned short* Wl1b = wbuf;
    unsigned short* Wl2b = wbuf + 16384;
    unsigned short* Wr2b = wbuf + 32768;

    // zero deg
    hipMemsetAsync(deg, 0, (size_t)N * 4, stream);

    // phase A: count + cvt_x(fp8) + cvt_w + graph_bounds + GEMM(x@Wr1^T)
    const int bCount = (E / 4 + 255) / 256;          // 977
    const int bCvtX  = (N * 64 / 8 + 255) / 256;     // 3125
    const int bCvtW  = 192;
    const int bGemm1 = (N + 127) / 128;              // 782
    k_phase_a<<<bCount + bCvtX + bCvtW + 1 + bGemm1, 256, 0, stream>>>(
        dst, deg, epos, E,
        x, xf8, N * 64,
        Wl1, Wr1, Wl2, Wr2, wbuf,
        batch, gstart, N, G,
        hr1, N,
        bCount, bCvtX, bCvtW);

    // scan + placement
    k_block_sum<<<nScanBlocks, 256, 0, stream>>>(deg, bsum, N);
    k_scan_bsum<<<1, 512, 0, stream>>>(bsum, nScanBlocks);
    k_scan_final<<<nScanBlocks, 256, 0, stream>>>(deg, bsum, row_start, N);
    k_place<<<(E / 8 + 255) / 256, 256, 0, stream>>>(src, dst, row_start, epos, csr_src, E);

    // layer 1: gather (fp8) -> linear Wl-half + hr1 (emits h1 bf16 + h1f8 fp8)
    k_gather1<<<(N + 3) / 4, 256, 0, stream>>>(xf8, row_start, csr_src, agg1, N);
    k_linear_l<64, true><<<(N + 127) / 128, 256, 0, stream>>>(
        agg1, Wl1b, bl1, hr1, h1, h1f8, N);

    // layer 2: gather2 + fused GEMM(h1@Wr2^T) in one launch, then linear
    const int bG2 = (N + 3) / 4;
    k_gather2_mix<<<bG2 + bGemm1, 256, 0, stream>>>(
        h1f8, row_start, csr_src, agg2, h1, Wr2b, hr2, N, bG2);
    k_linear_l<128, false><<<(N + 127) / 128, 256, 0, stream>>>(
        agg2, Wl2b, bl2, hr2, h2b, (unsigned char*)nullptr, N);

    // fused pool + head
    k_pool_head<<<G, 256, 0, stream>>>(h2b, gstart, Wout, bout, out);
}

// Round 15
// 316.556 us; speedup vs baseline: 1.2037x; 1.2037x over previous
//
#include <hip/hip_runtime.h>
#include <hip/hip_bf16.h>
#include <math.h>

typedef short short8_t __attribute__((ext_vector_type(8)));
typedef float floatx4  __attribute__((ext_vector_type(4)));
typedef float floatx2  __attribute__((ext_vector_type(2)));
typedef unsigned int uint;

// ---------------- bf16 helpers (RNE) ----------------------------------------

__device__ inline unsigned short f2b(float f) {
    uint u = __float_as_uint(f);
    u += 0x7fff + ((u >> 16) & 1);
    return (unsigned short)(u >> 16);
}
__device__ inline uint pack2(float a, float b) {
    return (uint)f2b(a) | ((uint)f2b(b) << 16);
}
__device__ inline float blo(uint v) { return __uint_as_float(v << 16); }
__device__ inline float bhi(uint v) { return __uint_as_float(v & 0xffff0000u); }

// ---------------- fp8 (e4m3) helpers ------------------------------------------

__device__ inline uint enc4_fp8(float f0, float f1, float f2, float f3) {
    uint v = __builtin_amdgcn_cvt_pk_fp8_f32(f0, f1, 0, false);
    v = __builtin_amdgcn_cvt_pk_fp8_f32(f2, f3, v, true);
    return v;
}
__device__ inline unsigned char enc1_fp8(float f) {
    return (unsigned char)(__builtin_amdgcn_cvt_pk_fp8_f32(f, f, 0, false) & 0xff);
}

// ---------------- phase A mega-kernel -----------------------------------------
// Lesson ledger:
//  R10: atomic count pinned ~45-50us regardless of ILP depth (4- vs 16-deep
//       identical) — atomic-unit throughput floor, <1% VALU, 11% HBM.
//  R13: 8-replica "XCD-local" histograms DON'T help — atomics execute at a
//       fixed home point, not the issuing XCD's L2.
//  R12: co-scheduling light work (cvt/bounds: 12 VGPR, 0 LDS) inside the
//       atomic launch is free — rides the idle CUs.
//  R11/R14: mixed-grid kernels take the WORST branch's VGPR/LDS allocation;
//       adding an MFMA branch (64 acc VGPRs + 8KB LDS) strangles the
//       occupancy the latency-bound branches need. Only fuse light branches.

__global__ __launch_bounds__(256) void k_phase_a(
    const int* __restrict__ dst, int* __restrict__ deg, int* __restrict__ epos, int E,
    const float* __restrict__ x, unsigned short* __restrict__ xb,
    unsigned char* __restrict__ xf8, int nX,
    const float* __restrict__ Wl1, const float* __restrict__ Wr1,
    const float* __restrict__ Wl2, const float* __restrict__ Wr2,
    unsigned short* __restrict__ wbuf,
    const int* __restrict__ batch, int* __restrict__ gstart, int N, int G,
    int bCount, int bCvtX, int bCvtW) {
    int b = blockIdx.x;
    if (b < bCount) {
        int e = (b * 256 + threadIdx.x) * 4;
        if (e + 3 < E) {
            int4 d4 = *(const int4*)(dst + e);
            int4 p;
            p.x = atomicAdd(&deg[d4.x], 1);
            p.y = atomicAdd(&deg[d4.y], 1);
            p.z = atomicAdd(&deg[d4.z], 1);
            p.w = atomicAdd(&deg[d4.w], 1);
            *(int4*)(epos + e) = p;
        } else {
            for (int k = e; k < E; ++k) epos[k] = atomicAdd(&deg[dst[k]], 1);
        }
    } else if (b < bCount + bCvtX) {
        int i = ((b - bCount) * 256 + threadIdx.x) * 8;
        if (i < nX) {
            float4 v0 = *(const float4*)(x + i);
            float4 v1 = *(const float4*)(x + i + 4);
            uint4 ob;
            ob.x = pack2(v0.x, v0.y);
            ob.y = pack2(v0.z, v0.w);
            ob.z = pack2(v1.x, v1.y);
            ob.w = pack2(v1.z, v1.w);
            *(uint4*)(xb + i) = ob;
            uint2 of;
            of.x = enc4_fp8(v0.x, v0.y, v0.z, v0.w);
            of.y = enc4_fp8(v1.x, v1.y, v1.z, v1.w);
            *(uint2*)(xf8 + i) = of;
        }
    } else if (b < bCount + bCvtX + bCvtW) {
        int i = (b - bCount - bCvtX) * 256 + threadIdx.x;
        if (i < 49152) {
            float v;
            if (i < 8192)       v = Wl1[i];
            else if (i < 16384) v = Wr1[i - 8192];
            else if (i < 32768) v = Wl2[i - 16384];
            else                v = Wr2[i - 32768];
            wbuf[i] = f2b(v);
        }
    } else {
        for (int g = threadIdx.x; g <= G; g += 256) {
            if (g == G) { gstart[G] = N; continue; }
            int lo = 0, hi = N;
            while (lo < hi) {
                int mid = (lo + hi) >> 1;
                if (batch[mid] < g) lo = mid + 1; else hi = mid;
            }
            gstart[g] = lo;
        }
    }
}

// ---------------- scan (3-phase) ----------------------------------------------

__global__ void k_block_sum(const int* __restrict__ deg, int* __restrict__ bsum, int n) {
    __shared__ int red[256];
    int i = blockIdx.x * 256 + threadIdx.x;
    red[threadIdx.x] = (i < n) ? deg[i] : 0;
    __syncthreads();
#pragma unroll
    for (int off = 128; off > 0; off >>= 1) {
        if (threadIdx.x < off) red[threadIdx.x] += red[threadIdx.x + off];
        __syncthreads();
    }
    if (threadIdx.x == 0) bsum[blockIdx.x] = red[0];
}

__global__ void k_scan_bsum(int* __restrict__ bsum, int nb) {
    __shared__ int s[512];
    int t = threadIdx.x;
    int v = (t < nb) ? bsum[t] : 0;
    s[t] = v;
    __syncthreads();
#pragma unroll
    for (int off = 1; off < 512; off <<= 1) {
        int u = (t >= off) ? s[t - off] : 0;
        __syncthreads();
        s[t] += u;
        __syncthreads();
    }
    if (t < nb) bsum[t] = s[t] - v;
}

__global__ void k_scan_final(const int* __restrict__ deg, const int* __restrict__ bsum,
                             int* __restrict__ row_start, int n) {
    __shared__ int s[256];
    int i = blockIdx.x * 256 + threadIdx.x;
    int v = (i < n) ? deg[i] : 0;
    s[threadIdx.x] = v;
    __syncthreads();
#pragma unroll
    for (int off = 1; off < 256; off <<= 1) {
        int u = (threadIdx.x >= off) ? s[threadIdx.x - off] : 0;
        __syncthreads();
        s[threadIdx.x] += u;
        __syncthreads();
    }
    int excl = s[threadIdx.x] - v + bsum[blockIdx.x];
    if (i < n) row_start[i] = excl;
    if (i == n - 1) row_start[n] = excl + v;
}

// atomic-free placement, 8 edges/thread. Packed CSR (4MB, L2-resident;
// R9 lesson: strided buckets caused 16x write amplification).
__global__ void k_place(const int* __restrict__ src, const int* __restrict__ dst,
                        const int* __restrict__ row_start, const int* __restrict__ epos,
                        int* __restrict__ csr_src, int E) {
    int e = (blockIdx.x * blockDim.x + threadIdx.x) * 8;
    if (e + 7 < E) {
        int4 d0 = *(const int4*)(dst + e);
        int4 d1 = *(const int4*)(dst + e + 4);
        int4 p0 = *(const int4*)(epos + e);
        int4 p1 = *(const int4*)(epos + e + 4);
        int4 s0 = *(const int4*)(src + e);
        int4 s1 = *(const int4*)(src + e + 4);
        int r0 = row_start[d0.x];
        int r1 = row_start[d0.y];
        int r2 = row_start[d0.z];
        int r3 = row_start[d0.w];
        int r4 = row_start[d1.x];
        int r5 = row_start[d1.y];
        int r6 = row_start[d1.z];
        int r7 = row_start[d1.w];
        csr_src[r0 + p0.x] = s0.x;
        csr_src[r1 + p0.y] = s0.y;
        csr_src[r2 + p0.z] = s0.z;
        csr_src[r3 + p0.w] = s0.w;
        csr_src[r4 + p1.x] = s1.x;
        csr_src[r5 + p1.y] = s1.y;
        csr_src[r6 + p1.z] = s1.z;
        csr_src[r7 + p1.w] = s1.w;
    } else {
        for (int k = e; k < E; ++k) csr_src[row_start[dst[k]] + epos[k]] = src[k];
    }
}

// ---------------- mean aggregation (fp8 in, bf16 out, fp32 accumulate) -------

#define ACCF8(v)                                                        \
    { floatx2 f = __builtin_amdgcn_cvt_pk_f32_fp8((v).x, false);        \
      a[0] += f[0]; a[1] += f[1];                                       \
      f = __builtin_amdgcn_cvt_pk_f32_fp8((v).x, true);                 \
      a[2] += f[0]; a[3] += f[1];                                       \
      f = __builtin_amdgcn_cvt_pk_f32_fp8((v).y, false);                \
      a[4] += f[0]; a[5] += f[1];                                       \
      f = __builtin_amdgcn_cvt_pk_f32_fp8((v).y, true);                 \
      a[6] += f[0]; a[7] += f[1]; }

// K=64: row = 64 B fp8. 8 edge-slots x 8 lanes x uint2; 2-deep unroll.
__global__ void k_gather1(const unsigned char* __restrict__ xf8,
                          const int* __restrict__ row_start,
                          const int* __restrict__ csr_src,
                          unsigned short* __restrict__ agg, int n_nodes) {
    int tid = threadIdx.x;
    int node = blockIdx.x * 4 + (tid >> 6);
    if (node >= n_nodes) return;
    int lane = tid & 63;
    int grp = lane >> 3;
    int lp  = lane & 7;
    int s = row_start[node];
    int e = row_start[node + 1];
    float a[8];
#pragma unroll
    for (int q = 0; q < 8; ++q) a[q] = 0.f;
    int i = s + grp;
    for (; i + 8 < e; i += 16) {
        int u0 = csr_src[i];
        int u1 = csr_src[i + 8];
        uint2 v0 = *(const uint2*)(xf8 + (size_t)u0 * 64 + lp * 8);
        uint2 v1 = *(const uint2*)(xf8 + (size_t)u1 * 64 + lp * 8);
        ACCF8(v0);
        ACCF8(v1);
    }
    if (i < e) {
        int u0 = csr_src[i];
        uint2 v0 = *(const uint2*)(xf8 + (size_t)u0 * 64 + lp * 8);
        ACCF8(v0);
    }
#pragma unroll
    for (int q = 0; q < 8; ++q) {
        a[q] += __shfl_xor(a[q], 8);
        a[q] += __shfl_xor(a[q], 16);
        a[q] += __shfl_xor(a[q], 32);
    }
    if (grp == 0) {
        int d = e - s;
        float scale = (d > 0) ? (1.f / (float)d) : 1.f;
        uint4 o;
        o.x = pack2(a[0] * scale, a[1] * scale);
        o.y = pack2(a[2] * scale, a[3] * scale);
        o.z = pack2(a[4] * scale, a[5] * scale);
        o.w = pack2(a[6] * scale, a[7] * scale);
        *(uint4*)(agg + (size_t)node * 64 + lp * 8) = o;
    }
}

// K=128: row = 128 B fp8. 4 edge-slots x 16 lanes x uint2; 2-deep unroll.
__global__ void k_gather2(const unsigned char* __restrict__ h1f8,
                          const int* __restrict__ row_start,
                          const int* __restrict__ csr_src,
                          unsigned short* __restrict__ agg, int n_nodes) {
    int tid = threadIdx.x;
    int node = blockIdx.x * 4 + (tid >> 6);
    if (node >= n_nodes) return;
    int lane = tid & 63;
    int grp = lane >> 4;
    int lp  = lane & 15;
    int s = row_start[node];
    int e = row_start[node + 1];
    float a[8];
#pragma unroll
    for (int q = 0; q < 8; ++q) a[q] = 0.f;
    int i = s + grp;
    for (; i + 4 < e; i += 8) {
        int u0 = csr_src[i];
        int u1 = csr_src[i + 4];
        uint2 v0 = *(const uint2*)(h1f8 + (size_t)u0 * 128 + lp * 8);
        uint2 v1 = *(const uint2*)(h1f8 + (size_t)u1 * 128 + lp * 8);
        ACCF8(v0);
        ACCF8(v1);
    }
    if (i < e) {
        int u0 = csr_src[i];
        uint2 v0 = *(const uint2*)(h1f8 + (size_t)u0 * 128 + lp * 8);
        ACCF8(v0);
    }
#pragma unroll
    for (int q = 0; q < 8; ++q) {
        a[q] += __shfl_xor(a[q], 16);
        a[q] += __shfl_xor(a[q], 32);
    }
    if (grp == 0) {
        int d = e - s;
        float scale = (d > 0) ? (1.f / (float)d) : 1.f;
        uint4 o;
        o.x = pack2(a[0] * scale, a[1] * scale);
        o.y = pack2(a[2] * scale, a[3] * scale);
        o.z = pack2(a[4] * scale, a[5] * scale);
        o.w = pack2(a[6] * scale, a[7] * scale);
        *(uint4*)(agg + (size_t)node * 128 + lp * 8) = o;
    }
}

// ---------------- MFMA SAGE linear: out = relu(agg@Wl.T + bl + xin@Wr.T) ----
// F8OUT: epilogue also emits fp8 copy (next layer's gather operand).

template <int K, bool F8OUT>
__global__ __launch_bounds__(256) void k_linear_mfma(
    const unsigned short* __restrict__ aggA, const unsigned short* __restrict__ xinA,
    const unsigned short* __restrict__ Wlb,  const float* __restrict__ bl,
    const unsigned short* __restrict__ Wrb,  unsigned short* __restrict__ out,
    unsigned char* __restrict__ outf8, int n_nodes) {
    constexpr int NCH = (2 * K) / 32;
    __shared__ __align__(16) short As[128 * 32];   // 8 KB

    int tid  = threadIdx.x;
    int lane = tid & 63;
    int wave = tid >> 6;
    int quad = lane >> 4;
    int lr   = lane & 15;
    int node0 = blockIdx.x * 128;

    floatx4 acc[8][2];
#pragma unroll
    for (int mi = 0; mi < 8; ++mi)
#pragma unroll
        for (int ni = 0; ni < 2; ++ni)
            acc[mi][ni] = (floatx4){0.f, 0.f, 0.f, 0.f};

    int srow = tid >> 2;
    int sslot = tid & 3;

#pragma unroll
    for (int c = 0; c < NCH; ++c) {
        const unsigned short* srcA;
        const unsigned short* srcW;
        int kb;
        if (c < K / 32) { srcA = aggA; srcW = Wlb; kb = c * 32; }
        else            { srcA = xinA; srcW = Wrb; kb = c * 32 - K; }

        __syncthreads();
        {
            int n1 = node0 + srow;       if (n1 >= n_nodes) n1 = n_nodes - 1;
            int n2 = node0 + srow + 64;  if (n2 >= n_nodes) n2 = n_nodes - 1;
            uint4 v1 = *(const uint4*)(srcA + (size_t)n1 * K + kb + sslot * 8);
            uint4 v2 = *(const uint4*)(srcA + (size_t)n2 * K + kb + sslot * 8);
            *(uint4*)(&As[srow * 32 + sslot * 8]) = v1;
            *(uint4*)(&As[(srow + 64) * 32 + sslot * 8]) = v2;
        }
        __syncthreads();

        short8_t bfrag[2];
#pragma unroll
        for (int ni = 0; ni < 2; ++ni) {
            int j = wave * 32 + ni * 16 + lr;
            bfrag[ni] = *(const short8_t*)(srcW + (size_t)j * K + kb + quad * 8);
        }
#pragma unroll
        for (int mi = 0; mi < 8; ++mi) {
            short8_t af = *(const short8_t*)(&As[(mi * 16 + lr) * 32 + quad * 8]);
            acc[mi][0] = __builtin_amdgcn_mfma_f32_16x16x32_bf16(af, bfrag[0], acc[mi][0], 0, 0, 0);
            acc[mi][1] = __builtin_amdgcn_mfma_f32_16x16x32_bf16(af, bfrag[1], acc[mi][1], 0, 0, 0);
        }
    }

    float b0 = bl[wave * 32 + lr];
    float b1 = bl[wave * 32 + 16 + lr];
    int j0 = wave * 32 + lr;
#pragma unroll
    for (int mi = 0; mi < 8; ++mi) {
#pragma unroll
        for (int r = 0; r < 4; ++r) {
            int node = node0 + mi * 16 + quad * 4 + r;
            if (node < n_nodes) {
                float v0 = fmaxf(acc[mi][0][r] + b0, 0.f);
                float v1 = fmaxf(acc[mi][1][r] + b1, 0.f);
                out[(size_t)node * 128 + j0]      = f2b(v0);
                out[(size_t)node * 128 + j0 + 16] = f2b(v1);
                if (F8OUT) {
                    outf8[(size_t)node * 128 + j0]      = enc1_fp8(v0);
                    outf8[(size_t)node * 128 + j0 + 16] = enc1_fp8(v1);
                }
            }
        }
    }
}

// ---------------- fused pool + head -------------------------------------------

__global__ __launch_bounds__(256) void k_pool_head(const unsigned short* __restrict__ h2b,
                                                   const int* __restrict__ gstart,
                                                   const float* __restrict__ Wout,
                                                   const float* __restrict__ bout,
                                                   float* __restrict__ out) {
    int g = blockIdx.x;
    int s = gstart[g], e = gstart[g + 1];
    int lane = threadIdx.x & 63;
    int wave = threadIdx.x >> 6;
    float ax = 0.f, ay = 0.f;
    for (int n = s + wave; n < e; n += 4) {
        uint v = ((const uint*)(h2b + (size_t)n * 128))[lane];
        ax += blo(v);
        ay += bhi(v);
    }
    __shared__ float2 red[4][64];
    red[wave][lane] = make_float2(ax, ay);
    __syncthreads();
    if (wave == 0) {
        float2 a = red[0][lane], b = red[1][lane], c = red[2][lane], d = red[3][lane];
        float cnt = (float)(e - s);
        float inv = (cnt > 0.f) ? (1.f / cnt) : 1.f;
        float px = (a.x + b.x + c.x + d.x) * inv;
        float py = (a.y + b.y + c.y + d.y) * inv;
        float2 w0 = ((const float2*)(Wout))[lane];
        float2 w1 = ((const float2*)(Wout + 128))[lane];
        float d0 = px * w0.x + py * w0.y;
        float d1 = px * w1.x + py * w1.y;
#pragma unroll
        for (int m = 32; m > 0; m >>= 1) {
            d0 += __shfl_xor(d0, m);
            d1 += __shfl_xor(d1, m);
        }
        if (lane == 0) {
            float l0 = d0 + bout[0];
            float l1 = d1 + bout[1];
            float mx = fmaxf(l0, l1);
            float lse = mx + logf(expf(l0 - mx) + expf(l1 - mx));
            out[g * 2 + 0] = l0 - lse;
            out[g * 2 + 1] = l1 - lse;
        }
    }
}

// ---------------- launch -----------------------------------------------------

static inline size_t alignUp(size_t x, size_t a) { return (x + a - 1) & ~(a - 1); }

extern "C" void kernel_launch(void* const* d_in, const int* in_sizes, int n_in,
                              void* d_out, int out_size, void* d_ws, size_t ws_size,
                              hipStream_t stream) {
    const float* x    = (const float*)d_in[0];
    const int*   ei   = (const int*)d_in[1];
    const int*   batch= (const int*)d_in[2];
    const float* Wl1  = (const float*)d_in[3];
    const float* bl1  = (const float*)d_in[4];
    const float* Wr1  = (const float*)d_in[5];
    const float* Wl2  = (const float*)d_in[6];
    const float* bl2  = (const float*)d_in[7];
    const float* Wr2  = (const float*)d_in[8];
    const float* Wout = (const float*)d_in[9];
    const float* bout = (const float*)d_in[10];
    float* out = (float*)d_out;

    const int N = in_sizes[0] / 64;   // 100000
    const int E = in_sizes[1] / 2;    // 1000000
    const int G = out_size / 2;       // 256

    const int* src = ei;
    const int* dst = ei + E;

    const int nScanBlocks = (N + 255) / 256;

    // workspace layout
    char* ws = (char*)d_ws;
    size_t off = 0;
    int*   deg       = (int*)(ws + off); off = alignUp(off + (size_t)N * 4, 256);
    int*   row_start = (int*)(ws + off); off = alignUp(off + (size_t)(N + 1) * 4, 256);
    int*   epos      = (int*)(ws + off); off = alignUp(off + (size_t)E * 4, 256);
    int*   csr_src   = (int*)(ws + off); off = alignUp(off + (size_t)E * 4, 256);
    int*   bsum      = (int*)(ws + off); off = alignUp(off + (size_t)512 * 4, 256);
    int*   gstart    = (int*)(ws + off); off = alignUp(off + (size_t)(G + 1) * 4, 256);
    unsigned short* xb   = (unsigned short*)(ws + off); off = alignUp(off + (size_t)N * 64 * 2, 256);
    unsigned char*  xf8  = (unsigned char*)(ws + off);  off = alignUp(off + (size_t)N * 64, 256);
    unsigned short* wbuf = (unsigned short*)(ws + off); off = alignUp(off + (size_t)49152 * 2, 256);
    unsigned short* agg1 = (unsigned short*)(ws + off); off = alignUp(off + (size_t)N * 64 * 2, 256);
    unsigned short* h1   = (unsigned short*)(ws + off); off = alignUp(off + (size_t)N * 128 * 2, 256);
    unsigned char*  h1f8 = (unsigned char*)(ws + off);  off = alignUp(off + (size_t)N * 128, 256);
    unsigned short* agg2 = (unsigned short*)(ws + off); off = alignUp(off + (size_t)N * 128 * 2, 256);
    unsigned short* h2b  = (unsigned short*)(ws + off); off = alignUp(off + (size_t)N * 128 * 2, 256);
    (void)ws_size;

    unsigned short* Wl1b = wbuf;
    unsigned short* Wr1b = wbuf + 8192;
    unsigned short* Wl2b = wbuf + 16384;
    unsigned short* Wr2b = wbuf + 32768;

    // zero deg
    hipMemsetAsync(deg, 0, (size_t)N * 4, stream);

    // phase A: count_pos + cvt_x + cvt_w + graph_bounds in one launch
    const int bCount = (E / 4 + 255) / 256;          // 977
    const int bCvtX  = (N * 64 / 8 + 255) / 256;     // 3125
    const int bCvtW  = 192;
    k_phase_a<<<bCount + bCvtX + bCvtW + 1, 256, 0, stream>>>(
        dst, deg, epos, E,
        x, xb, xf8, N * 64,
        Wl1, Wr1, Wl2, Wr2, wbuf,
        batch, gstart, N, G,
        bCount, bCvtX, bCvtW);

    // scan + placement
    k_block_sum<<<nScanBlocks, 256, 0, stream>>>(deg, bsum, N);
    k_scan_bsum<<<1, 512, 0, stream>>>(bsum, nScanBlocks);
    k_scan_final<<<nScanBlocks, 256, 0, stream>>>(deg, bsum, row_start, N);
    k_place<<<(E / 8 + 255) / 256, 256, 0, stream>>>(src, dst, row_start, epos, csr_src, E);

    // layer 1: gather (fp8) -> MFMA linear (emits h1 bf16 + h1f8 fp8)
    k_gather1<<<(N + 3) / 4, 256, 0, stream>>>(xf8, row_start, csr_src, agg1, N);
    k_linear_mfma<64, true><<<(N + 127) / 128, 256, 0, stream>>>(
        agg1, xb, Wl1b, bl1, Wr1b, h1, h1f8, N);

    // layer 2
    k_gather2<<<(N + 3) / 4, 256, 0, stream>>>(h1f8, row_start, csr_src, agg2, N);
    k_linear_mfma<128, false><<<(N + 127) / 128, 256, 0, stream>>>(
        agg2, h1, Wl2b, bl2, Wr2b, h2b, (unsigned char*)nullptr, N);

    // fused pool + head
    k_pool_head<<<G, 256, 0, stream>>>(h2b, gstart, Wout, bout, out);
}

// Round 16
// 287.007 us; speedup vs baseline: 1.3276x; 1.1030x over previous
//
#include <hip/hip_runtime.h>
#include <hip/hip_bf16.h>
#include <math.h>

typedef short short8_t __attribute__((ext_vector_type(8)));
typedef float floatx4  __attribute__((ext_vector_type(4)));
typedef float floatx2  __attribute__((ext_vector_type(2)));
typedef unsigned int uint;

#define EPB 1024   // edges per histogram/scatter block
#define BSH 9      // 512 nodes per coarse bucket

// ---------------- bf16 helpers (RNE) ----------------------------------------

__device__ inline unsigned short f2b(float f) {
    uint u = __float_as_uint(f);
    u += 0x7fff + ((u >> 16) & 1);
    return (unsigned short)(u >> 16);
}
__device__ inline uint pack2(float a, float b) {
    return (uint)f2b(a) | ((uint)f2b(b) << 16);
}
__device__ inline float blo(uint v) { return __uint_as_float(v << 16); }
__device__ inline float bhi(uint v) { return __uint_as_float(v & 0xffff0000u); }

// ---------------- fp8 (e4m3) helpers ------------------------------------------

__device__ inline uint enc4_fp8(float f0, float f1, float f2, float f3) {
    uint v = __builtin_amdgcn_cvt_pk_fp8_f32(f0, f1, 0, false);
    v = __builtin_amdgcn_cvt_pk_fp8_f32(f2, f3, v, true);
    return v;
}
__device__ inline unsigned char enc1_fp8(float f) {
    return (unsigned char)(__builtin_amdgcn_cvt_pk_fp8_f32(f, f, 0, false) & 0xff);
}

// ---------------- CSR via bucketed counting sort ------------------------------
// Lesson ledger:
//  R10/R13: GLOBAL atomic histogram pinned ~43-50us (ILP- and replication-
//       invariant, ~23 G atomics/s, <2% VALU / 16% HBM) — algorithmic cost,
//       not a pipe limit. This round: eliminate global atomics entirely.
//  R12: co-scheduling light branches (<=1KB LDS, low VGPR) in one grid is free.
//  R11/R14: never mix an MFMA branch into a latency-bound grid (worst-branch
//       VGPR/LDS allocation kills occupancy).
//  R9: scattered 4B stores into a >L2 strided region -> 16x write amp; keep
//       scatter targets packed (4MB, L2-resident).

// phase A: per-block LDS histogram over coarse buckets + cvt_x + cvt_w + bounds
__global__ __launch_bounds__(256) void k_phase_a(
    const int* __restrict__ dst, int* __restrict__ bhist, int E,
    const float* __restrict__ x, unsigned short* __restrict__ xb,
    unsigned char* __restrict__ xf8, int nX,
    const float* __restrict__ Wl1, const float* __restrict__ Wr1,
    const float* __restrict__ Wl2, const float* __restrict__ Wr2,
    unsigned short* __restrict__ wbuf,
    const int* __restrict__ batch, int* __restrict__ gstart, int N, int G,
    int bHist, int bCvtX, int bCvtW) {
    __shared__ int h[256];
    int b = blockIdx.x;
    int tid = threadIdx.x;
    if (b < bHist) {
        h[tid] = 0;
        __syncthreads();
        int e = b * EPB + tid * 4;
        if (e + 3 < E) {
            int4 d4 = *(const int4*)(dst + e);
            atomicAdd(&h[d4.x >> BSH], 1);
            atomicAdd(&h[d4.y >> BSH], 1);
            atomicAdd(&h[d4.z >> BSH], 1);
            atomicAdd(&h[d4.w >> BSH], 1);
        } else {
            for (int k = e; k < E; ++k) atomicAdd(&h[dst[k] >> BSH], 1);
        }
        __syncthreads();
        bhist[(size_t)b * 256 + tid] = h[tid];
    } else if (b < bHist + bCvtX) {
        int i = ((b - bHist) * 256 + tid) * 8;
        if (i < nX) {
            float4 v0 = *(const float4*)(x + i);
            float4 v1 = *(const float4*)(x + i + 4);
            uint4 ob;
            ob.x = pack2(v0.x, v0.y);
            ob.y = pack2(v0.z, v0.w);
            ob.z = pack2(v1.x, v1.y);
            ob.w = pack2(v1.z, v1.w);
            *(uint4*)(xb + i) = ob;
            uint2 of;
            of.x = enc4_fp8(v0.x, v0.y, v0.z, v0.w);
            of.y = enc4_fp8(v1.x, v1.y, v1.z, v1.w);
            *(uint2*)(xf8 + i) = of;
        }
    } else if (b < bHist + bCvtX + bCvtW) {
        int i = (b - bHist - bCvtX) * 256 + tid;
        if (i < 49152) {
            float v;
            if (i < 8192)       v = Wl1[i];
            else if (i < 16384) v = Wr1[i - 8192];
            else if (i < 32768) v = Wl2[i - 16384];
            else                v = Wr2[i - 32768];
            wbuf[i] = f2b(v);
        }
    } else {
        for (int g = tid; g <= G; g += 256) {
            if (g == G) { gstart[G] = N; continue; }
            int lo = 0, hi = N;
            while (lo < hi) {
                int mid = (lo + hi) >> 1;
                if (batch[mid] < g) lo = mid + 1; else hi = mid;
            }
            gstart[g] = lo;
        }
    }
}

// column scan: for bucket k, exclusive-prefix bhist[:,k] over blocks; btot[k]=total
__global__ __launch_bounds__(256) void k_scan_bh(int* __restrict__ bhist,
                                                 int* __restrict__ btot, int nb) {
    __shared__ int ss[256];
    int k = blockIdx.x;
    int t = threadIdx.x;
    int b0 = t * 4;
    int v[4];
    int sum = 0;
#pragma unroll
    for (int i = 0; i < 4; ++i) {
        int b = b0 + i;
        v[i] = (b < nb) ? bhist[(size_t)b * 256 + k] : 0;
        sum += v[i];
    }
    ss[t] = sum;
    __syncthreads();
#pragma unroll
    for (int off = 1; off < 256; off <<= 1) {
        int u = (t >= off) ? ss[t - off] : 0;
        __syncthreads();
        ss[t] += u;
        __syncthreads();
    }
    int run = ss[t] - sum;
#pragma unroll
    for (int i = 0; i < 4; ++i) {
        int b = b0 + i;
        if (b < nb) { bhist[(size_t)b * 256 + k] = run; run += v[i]; }
    }
    if (t == 0) btot[k] = ss[255];
}

// exclusive scan of 256 bucket totals -> bbase[0..256]; also row_start[N]=E
__global__ void k_scan_btot(const int* __restrict__ btot, int* __restrict__ bbase,
                            int* __restrict__ row_start, int N, int E) {
    __shared__ int ss[256];
    int t = threadIdx.x;
    int v = btot[t];
    ss[t] = v;
    __syncthreads();
#pragma unroll
    for (int off = 1; off < 256; off <<= 1) {
        int u = (t >= off) ? ss[t - off] : 0;
        __syncthreads();
        ss[t] += u;
        __syncthreads();
    }
    bbase[t] = ss[t] - v;
    if (t == 255) bbase[256] = ss[255];
    if (t == 0) row_start[N] = E;
}

// scatter edges into bucket-grouped ebuf; positions via LDS cursors (no global atomics)
// record = (dst&511)<<23 | src   (requires src < 2^23)
__global__ __launch_bounds__(256) void k_scatter_b(
    const int* __restrict__ src, const int* __restrict__ dst,
    const int* __restrict__ bhist, const int* __restrict__ bbase,
    int* __restrict__ ebuf, int E) {
    __shared__ int lbase[256];
    int b = blockIdx.x;
    int t = threadIdx.x;
    lbase[t] = bbase[t] + bhist[(size_t)b * 256 + t];
    __syncthreads();
    int e = b * EPB + t * 4;
    if (e + 3 < E) {
        int4 d4 = *(const int4*)(dst + e);
        int4 s4 = *(const int4*)(src + e);
        int k, p;
        k = d4.x >> BSH; p = atomicAdd(&lbase[k], 1); ebuf[p] = ((d4.x & 511) << 23) | s4.x;
        k = d4.y >> BSH; p = atomicAdd(&lbase[k], 1); ebuf[p] = ((d4.y & 511) << 23) | s4.y;
        k = d4.z >> BSH; p = atomicAdd(&lbase[k], 1); ebuf[p] = ((d4.z & 511) << 23) | s4.z;
        k = d4.w >> BSH; p = atomicAdd(&lbase[k], 1); ebuf[p] = ((d4.w & 511) << 23) | s4.w;
    } else {
        for (int q = e; q < E; ++q) {
            int d = dst[q];
            int p = atomicAdd(&lbase[d >> BSH], 1);
            ebuf[p] = ((d & 511) << 23) | src[q];
        }
    }
}

// per-bucket counting sort: 512-bin LDS histogram + scan -> row_start + csr_src
__global__ __launch_bounds__(256) void k_bucket_csr(
    const int* __restrict__ ebuf, const int* __restrict__ bbase,
    int* __restrict__ row_start, int* __restrict__ csr_src, int N) {
    __shared__ int h2[512];
    __shared__ int ss[256];
    int k = blockIdx.x;
    int t = threadIdx.x;
    int node0 = k << BSH;
    int nn = N - node0; if (nn > 512) nn = 512;
    int s = bbase[k], e = bbase[k + 1];
    h2[t] = 0; h2[t + 256] = 0;
    __syncthreads();
    for (int i = s + t; i < e; i += 256)
        atomicAdd(&h2[((uint)ebuf[i]) >> 23], 1);
    __syncthreads();
    int a0 = h2[2 * t], a1 = h2[2 * t + 1];
    int ps = a0 + a1;
    ss[t] = ps;
    __syncthreads();
#pragma unroll
    for (int off = 1; off < 256; off <<= 1) {
        int u = (t >= off) ? ss[t - off] : 0;
        __syncthreads();
        ss[t] += u;
        __syncthreads();
    }
    int base = ss[t] - ps;
    h2[2 * t] = base;
    h2[2 * t + 1] = base + a0;
    __syncthreads();
    int rs0 = h2[t];
    int rs1 = h2[t + 256];
    __syncthreads();
    if (t < nn)       row_start[node0 + t]       = s + rs0;
    if (t + 256 < nn) row_start[node0 + t + 256] = s + rs1;
    for (int i = s + t; i < e; i += 256) {
        int rec = ebuf[i];
        int j = ((uint)rec) >> 23;
        int pos = atomicAdd(&h2[j], 1);
        csr_src[s + pos] = rec & 0x7FFFFF;
    }
}

// ---------------- mean aggregation (fp8 in, bf16 out, fp32 accumulate) -------

#define ACCF8(v)                                                        \
    { floatx2 f = __builtin_amdgcn_cvt_pk_f32_fp8((v).x, false);        \
      a[0] += f[0]; a[1] += f[1];                                       \
      f = __builtin_amdgcn_cvt_pk_f32_fp8((v).x, true);                 \
      a[2] += f[0]; a[3] += f[1];                                       \
      f = __builtin_amdgcn_cvt_pk_f32_fp8((v).y, false);                \
      a[4] += f[0]; a[5] += f[1];                                       \
      f = __builtin_amdgcn_cvt_pk_f32_fp8((v).y, true);                 \
      a[6] += f[0]; a[7] += f[1]; }

// K=64: row = 64 B fp8. 8 edge-slots x 8 lanes x uint2; 2-deep unroll.
__global__ void k_gather1(const unsigned char* __restrict__ xf8,
                          const int* __restrict__ row_start,
                          const int* __restrict__ csr_src,
                          unsigned short* __restrict__ agg, int n_nodes) {
    int tid = threadIdx.x;
    int node = blockIdx.x * 4 + (tid >> 6);
    if (node >= n_nodes) return;
    int lane = tid & 63;
    int grp = lane >> 3;
    int lp  = lane & 7;
    int s = row_start[node];
    int e = row_start[node + 1];
    float a[8];
#pragma unroll
    for (int q = 0; q < 8; ++q) a[q] = 0.f;
    int i = s + grp;
    for (; i + 8 < e; i += 16) {
        int u0 = csr_src[i];
        int u1 = csr_src[i + 8];
        uint2 v0 = *(const uint2*)(xf8 + (size_t)u0 * 64 + lp * 8);
        uint2 v1 = *(const uint2*)(xf8 + (size_t)u1 * 64 + lp * 8);
        ACCF8(v0);
        ACCF8(v1);
    }
    if (i < e) {
        int u0 = csr_src[i];
        uint2 v0 = *(const uint2*)(xf8 + (size_t)u0 * 64 + lp * 8);
        ACCF8(v0);
    }
#pragma unroll
    for (int q = 0; q < 8; ++q) {
        a[q] += __shfl_xor(a[q], 8);
        a[q] += __shfl_xor(a[q], 16);
        a[q] += __shfl_xor(a[q], 32);
    }
    if (grp == 0) {
        int d = e - s;
        float scale = (d > 0) ? (1.f / (float)d) : 1.f;
        uint4 o;
        o.x = pack2(a[0] * scale, a[1] * scale);
        o.y = pack2(a[2] * scale, a[3] * scale);
        o.z = pack2(a[4] * scale, a[5] * scale);
        o.w = pack2(a[6] * scale, a[7] * scale);
        *(uint4*)(agg + (size_t)node * 64 + lp * 8) = o;
    }
}

// K=128: row = 128 B fp8. 4 edge-slots x 16 lanes x uint2; 2-deep unroll.
__global__ void k_gather2(const unsigned char* __restrict__ h1f8,
                          const int* __restrict__ row_start,
                          const int* __restrict__ csr_src,
                          unsigned short* __restrict__ agg, int n_nodes) {
    int tid = threadIdx.x;
    int node = blockIdx.x * 4 + (tid >> 6);
    if (node >= n_nodes) return;
    int lane = tid & 63;
    int grp = lane >> 4;
    int lp  = lane & 15;
    int s = row_start[node];
    int e = row_start[node + 1];
    float a[8];
#pragma unroll
    for (int q = 0; q < 8; ++q) a[q] = 0.f;
    int i = s + grp;
    for (; i + 4 < e; i += 8) {
        int u0 = csr_src[i];
        int u1 = csr_src[i + 4];
        uint2 v0 = *(const uint2*)(h1f8 + (size_t)u0 * 128 + lp * 8);
        uint2 v1 = *(const uint2*)(h1f8 + (size_t)u1 * 128 + lp * 8);
        ACCF8(v0);
        ACCF8(v1);
    }
    if (i < e) {
        int u0 = csr_src[i];
        uint2 v0 = *(const uint2*)(h1f8 + (size_t)u0 * 128 + lp * 8);
        ACCF8(v0);
    }
#pragma unroll
    for (int q = 0; q < 8; ++q) {
        a[q] += __shfl_xor(a[q], 16);
        a[q] += __shfl_xor(a[q], 32);
    }
    if (grp == 0) {
        int d = e - s;
        float scale = (d > 0) ? (1.f / (float)d) : 1.f;
        uint4 o;
        o.x = pack2(a[0] * scale, a[1] * scale);
        o.y = pack2(a[2] * scale, a[3] * scale);
        o.z = pack2(a[4] * scale, a[5] * scale);
        o.w = pack2(a[6] * scale, a[7] * scale);
        *(uint4*)(agg + (size_t)node * 128 + lp * 8) = o;
    }
}

// ---------------- MFMA SAGE linear: out = relu(agg@Wl.T + bl + xin@Wr.T) ----
// F8OUT: epilogue also emits fp8 copy (next layer's gather operand).

template <int K, bool F8OUT>
__global__ __launch_bounds__(256) void k_linear_mfma(
    const unsigned short* __restrict__ aggA, const unsigned short* __restrict__ xinA,
    const unsigned short* __restrict__ Wlb,  const float* __restrict__ bl,
    const unsigned short* __restrict__ Wrb,  unsigned short* __restrict__ out,
    unsigned char* __restrict__ outf8, int n_nodes) {
    constexpr int NCH = (2 * K) / 32;
    __shared__ __align__(16) short As[128 * 32];   // 8 KB

    int tid  = threadIdx.x;
    int lane = tid & 63;
    int wave = tid >> 6;
    int quad = lane >> 4;
    int lr   = lane & 15;
    int node0 = blockIdx.x * 128;

    floatx4 acc[8][2];
#pragma unroll
    for (int mi = 0; mi < 8; ++mi)
#pragma unroll
        for (int ni = 0; ni < 2; ++ni)
            acc[mi][ni] = (floatx4){0.f, 0.f, 0.f, 0.f};

    int srow = tid >> 2;
    int sslot = tid & 3;

#pragma unroll
    for (int c = 0; c < NCH; ++c) {
        const unsigned short* srcA;
        const unsigned short* srcW;
        int kb;
        if (c < K / 32) { srcA = aggA; srcW = Wlb; kb = c * 32; }
        else            { srcA = xinA; srcW = Wrb; kb = c * 32 - K; }

        __syncthreads();
        {
            int n1 = node0 + srow;       if (n1 >= n_nodes) n1 = n_nodes - 1;
            int n2 = node0 + srow + 64;  if (n2 >= n_nodes) n2 = n_nodes - 1;
            uint4 v1 = *(const uint4*)(srcA + (size_t)n1 * K + kb + sslot * 8);
            uint4 v2 = *(const uint4*)(srcA + (size_t)n2 * K + kb + sslot * 8);
            *(uint4*)(&As[srow * 32 + sslot * 8]) = v1;
            *(uint4*)(&As[(srow + 64) * 32 + sslot * 8]) = v2;
        }
        __syncthreads();

        short8_t bfrag[2];
#pragma unroll
        for (int ni = 0; ni < 2; ++ni) {
            int j = wave * 32 + ni * 16 + lr;
            bfrag[ni] = *(const short8_t*)(srcW + (size_t)j * K + kb + quad * 8);
        }
#pragma unroll
        for (int mi = 0; mi < 8; ++mi) {
            short8_t af = *(const short8_t*)(&As[(mi * 16 + lr) * 32 + quad * 8]);
            acc[mi][0] = __builtin_amdgcn_mfma_f32_16x16x32_bf16(af, bfrag[0], acc[mi][0], 0, 0, 0);
            acc[mi][1] = __builtin_amdgcn_mfma_f32_16x16x32_bf16(af, bfrag[1], acc[mi][1], 0, 0, 0);
        }
    }

    float b0 = bl[wave * 32 + lr];
    float b1 = bl[wave * 32 + 16 + lr];
    int j0 = wave * 32 + lr;
#pragma unroll
    for (int mi = 0; mi < 8; ++mi) {
#pragma unroll
        for (int r = 0; r < 4; ++r) {
            int node = node0 + mi * 16 + quad * 4 + r;
            if (node < n_nodes) {
                float v0 = fmaxf(acc[mi][0][r] + b0, 0.f);
                float v1 = fmaxf(acc[mi][1][r] + b1, 0.f);
                out[(size_t)node * 128 + j0]      = f2b(v0);
                out[(size_t)node * 128 + j0 + 16] = f2b(v1);
                if (F8OUT) {
                    outf8[(size_t)node * 128 + j0]      = enc1_fp8(v0);
                    outf8[(size_t)node * 128 + j0 + 16] = enc1_fp8(v1);
                }
            }
        }
    }
}

// ---------------- fused pool + head -------------------------------------------

__global__ __launch_bounds__(256) void k_pool_head(const unsigned short* __restrict__ h2b,
                                                   const int* __restrict__ gstart,
                                                   const float* __restrict__ Wout,
                                                   const float* __restrict__ bout,
                                                   float* __restrict__ out) {
    int g = blockIdx.x;
    int s = gstart[g], e = gstart[g + 1];
    int lane = threadIdx.x & 63;
    int wave = threadIdx.x >> 6;
    float ax = 0.f, ay = 0.f;
    for (int n = s + wave; n < e; n += 4) {
        uint v = ((const uint*)(h2b + (size_t)n * 128))[lane];
        ax += blo(v);
        ay += bhi(v);
    }
    __shared__ float2 red[4][64];
    red[wave][lane] = make_float2(ax, ay);
    __syncthreads();
    if (wave == 0) {
        float2 a = red[0][lane], b = red[1][lane], c = red[2][lane], d = red[3][lane];
        float cnt = (float)(e - s);
        float inv = (cnt > 0.f) ? (1.f / cnt) : 1.f;
        float px = (a.x + b.x + c.x + d.x) * inv;
        float py = (a.y + b.y + c.y + d.y) * inv;
        float2 w0 = ((const float2*)(Wout))[lane];
        float2 w1 = ((const float2*)(Wout + 128))[lane];
        float d0 = px * w0.x + py * w0.y;
        float d1 = px * w1.x + py * w1.y;
#pragma unroll
        for (int m = 32; m > 0; m >>= 1) {
            d0 += __shfl_xor(d0, m);
            d1 += __shfl_xor(d1, m);
        }
        if (lane == 0) {
            float l0 = d0 + bout[0];
            float l1 = d1 + bout[1];
            float mx = fmaxf(l0, l1);
            float lse = mx + logf(expf(l0 - mx) + expf(l1 - mx));
            out[g * 2 + 0] = l0 - lse;
            out[g * 2 + 1] = l1 - lse;
        }
    }
}

// ---------------- launch -----------------------------------------------------

static inline size_t alignUp(size_t x, size_t a) { return (x + a - 1) & ~(a - 1); }

extern "C" void kernel_launch(void* const* d_in, const int* in_sizes, int n_in,
                              void* d_out, int out_size, void* d_ws, size_t ws_size,
                              hipStream_t stream) {
    const float* x    = (const float*)d_in[0];
    const int*   ei   = (const int*)d_in[1];
    const int*   batch= (const int*)d_in[2];
    const float* Wl1  = (const float*)d_in[3];
    const float* bl1  = (const float*)d_in[4];
    const float* Wr1  = (const float*)d_in[5];
    const float* Wl2  = (const float*)d_in[6];
    const float* bl2  = (const float*)d_in[7];
    const float* Wr2  = (const float*)d_in[8];
    const float* Wout = (const float*)d_in[9];
    const float* bout = (const float*)d_in[10];
    float* out = (float*)d_out;

    const int N = in_sizes[0] / 64;   // 100000 (must be < 2^23 for record packing)
    const int E = in_sizes[1] / 2;    // 1000000
    const int G = out_size / 2;       // 256

    const int* src = ei;
    const int* dst = ei + E;

    const int bHist = (E + EPB - 1) / EPB;     // 977
    const int NB    = (N + 511) >> BSH;        // 196 coarse buckets

    // workspace layout
    char* ws = (char*)d_ws;
    size_t off = 0;
    int*   bhist     = (int*)(ws + off); off = alignUp(off + (size_t)bHist * 256 * 4, 256);
    int*   btot      = (int*)(ws + off); off = alignUp(off + (size_t)257 * 4, 256);
    int*   bbase     = (int*)(ws + off); off = alignUp(off + (size_t)257 * 4, 256);
    int*   row_start = (int*)(ws + off); off = alignUp(off + (size_t)(N + 1) * 4, 256);
    int*   ebuf      = (int*)(ws + off); off = alignUp(off + (size_t)E * 4, 256);
    int*   csr_src   = (int*)(ws + off); off = alignUp(off + (size_t)E * 4, 256);
    int*   gstart    = (int*)(ws + off); off = alignUp(off + (size_t)(G + 1) * 4, 256);
    unsigned short* xb   = (unsigned short*)(ws + off); off = alignUp(off + (size_t)N * 64 * 2, 256);
    unsigned char*  xf8  = (unsigned char*)(ws + off);  off = alignUp(off + (size_t)N * 64, 256);
    unsigned short* wbuf = (unsigned short*)(ws + off); off = alignUp(off + (size_t)49152 * 2, 256);
    unsigned short* agg1 = (unsigned short*)(ws + off); off = alignUp(off + (size_t)N * 64 * 2, 256);
    unsigned short* h1   = (unsigned short*)(ws + off); off = alignUp(off + (size_t)N * 128 * 2, 256);
    unsigned char*  h1f8 = (unsigned char*)(ws + off);  off = alignUp(off + (size_t)N * 128, 256);
    unsigned short* agg2 = (unsigned short*)(ws + off); off = alignUp(off + (size_t)N * 128 * 2, 256);
    unsigned short* h2b  = (unsigned short*)(ws + off); off = alignUp(off + (size_t)N * 128 * 2, 256);
    (void)ws_size;

    unsigned short* Wl1b = wbuf;
    unsigned short* Wr1b = wbuf + 8192;
    unsigned short* Wl2b = wbuf + 16384;
    unsigned short* Wr2b = wbuf + 32768;

    // phase A: LDS bucket histogram + cvt_x + cvt_w + graph_bounds (no memset needed)
    const int bCvtX = (N * 64 / 8 + 255) / 256;     // 3125
    const int bCvtW = 192;
    k_phase_a<<<bHist + bCvtX + bCvtW + 1, 256, 0, stream>>>(
        dst, bhist, E,
        x, xb, xf8, N * 64,
        Wl1, Wr1, Wl2, Wr2, wbuf,
        batch, gstart, N, G,
        bHist, bCvtX, bCvtW);

    // bucket scans + bucket-grouped scatter + per-bucket counting sort
    k_scan_bh<<<256, 256, 0, stream>>>(bhist, btot, bHist);
    k_scan_btot<<<1, 256, 0, stream>>>(btot, bbase, row_start, N, E);
    k_scatter_b<<<bHist, 256, 0, stream>>>(src, dst, bhist, bbase, ebuf, E);
    k_bucket_csr<<<NB, 256, 0, stream>>>(ebuf, bbase, row_start, csr_src, N);

    // layer 1: gather (fp8) -> MFMA linear (emits h1 bf16 + h1f8 fp8)
    k_gather1<<<(N + 3) / 4, 256, 0, stream>>>(xf8, row_start, csr_src, agg1, N);
    k_linear_mfma<64, true><<<(N + 127) / 128, 256, 0, stream>>>(
        agg1, xb, Wl1b, bl1, Wr1b, h1, h1f8, N);

    // layer 2
    k_gather2<<<(N + 3) / 4, 256, 0, stream>>>(h1f8, row_start, csr_src, agg2, N);
    k_linear_mfma<128, false><<<(N + 127) / 128, 256, 0, stream>>>(
        agg2, h1, Wl2b, bl2, Wr2b, h2b, (unsigned char*)nullptr, N);

    // fused pool + head
    k_pool_head<<<G, 256, 0, stream>>>(h2b, gstart, Wout, bout, out);
}